// Round 6
// baseline (479.122 us; speedup 1.0000x reference)
//
#include <hip/hip_runtime.h>
#include <hip/hip_bf16.h>
#include <math.h>
#include <stdint.h>

#define NB 4
#define NN 2048
#define NA 128
#define RMINF 5.8f
#define RMAXF 6.0f
#define PI_OVER_DR 15.707963267948966f  /* pi / (RMAX-RMIN) */

typedef __attribute__((ext_vector_type(8))) short short8v;   // 8 bf16 (MFMA A/B frag)
typedef __attribute__((ext_vector_type(4))) float f32x4;     // MFMA C/D frag

// Exact tanh via exp: tanh(x) = 1 - 2/(e^{2x}+1). ~7 VALU inst, rel err ~1e-6.
__device__ __forceinline__ float fast_tanh(float x)
{
    x = fminf(fmaxf(x, -15.f), 15.f);
    float e = __expf(2.f * x);
    float r = __builtin_amdgcn_rcpf(e + 1.f);
    return fmaf(-2.f, r, 1.f);
}

__device__ __forceinline__ uint16_t bf16_of(float x)
{
    __hip_bfloat16 b = __float2bfloat16(x);
    return *(uint16_t*)&b;
}

__device__ __forceinline__ float bf16_to_f(uint16_t v)
{
    union { uint32_t u; float f; } c; c.u = ((uint32_t)v) << 16; return c.f;
}

__device__ __forceinline__ uint32_t pack2(uint16_t lo, uint16_t hi)
{
    return (uint32_t)lo | ((uint32_t)hi << 16);
}

// ---------------------------------------------------------------------------
// Prep 1: We2 [50][100] fp32 -> We2Hi/We2Lo [112][64] bf16 (transposed, padded).
// ---------------------------------------------------------------------------
__global__ void prep_kernel(const float* __restrict__ We2,
                            uint16_t* __restrict__ We2Hi,
                            uint16_t* __restrict__ We2Lo)
{
    int idx = blockIdx.x * 256 + threadIdx.x;
    if (idx < 112 * 64) {
        int j = idx >> 6, k = idx & 63;
        float v = (j < 100 && k < 50) ? We2[k * 100 + j] : 0.f;
        uint16_t hi = bf16_of(v);
        We2Hi[idx] = hi;
        We2Lo[idx] = bf16_of(v - bf16_to_f(hi));
    }
}

// ---------------------------------------------------------------------------
// Prep 2: fitting weight W [K][240] fp32 -> Wt hi/lo [256][KP] bf16
// (transposed, zero-padded in both N (240->256) and K (K->KP)).
// ---------------------------------------------------------------------------
__global__ void prep_wt_kernel(const float* __restrict__ W,
                               uint16_t* __restrict__ Whi,
                               uint16_t* __restrict__ Wlo,
                               int K, int KP)
{
    int idx = blockIdx.x * 256 + threadIdx.x;
    if (idx < 256 * KP) {
        int colN = idx / KP, k = idx - colN * KP;
        float v = (colN < 240 && k < K) ? W[k * 240 + colN] : 0.f;
        uint16_t hi = bf16_of(v);
        Whi[idx] = hi;
        Wlo[idx] = bf16_of(v - bf16_to_f(hi));
    }
}

// ---------------------------------------------------------------------------
// Per-atom kernel v6: We2 B-frags stream straight from global (28 KB total ->
// L1-resident after first block); LDS = h2s 16K (phased hi/lo, reused as
// tmpPart) + RiSh 2K + tmpBf 2K -> ~20.5 KB -> 6 blocks/CU.
// ---------------------------------------------------------------------------
__global__ __launch_bounds__(256, 6) void embed_kernel(
    const float* __restrict__ dR, const int* __restrict__ neigh,
    const float* __restrict__ We0, const float* __restrict__ be0,
    const float* __restrict__ We1, const float* __restrict__ be1,
    const uint16_t* __restrict__ We2Hi, const uint16_t* __restrict__ We2Lo,
    const float* __restrict__ be2,
    uint16_t* __restrict__ DRhi, uint16_t* __restrict__ DRlo)
{
    const int atom = blockIdx.x;
    const int t = threadIdx.x;
    const int half = t >> 7;
    const int u = t & 127;          // neighbor index
    const int lane = t & 63;
    const int wid = t >> 6;

    __shared__ __align__(16) char smem[16384];
    __shared__ float4 RiSh[128];
    __shared__ float  tmpBf[4][128];
    __shared__ unsigned long long balls[2];

    char* h2s = smem;               // [128]x128B bf16, XOR-swizzled (hi, then lo)
    float* tmpPart = (float*)smem;  // after MFMA: [4 waves][4 c][128 col] f32

    // ---- phase 0: S_Rij, mask, ballot ----
    const int base = atom * NA;
    float x = dR[(base + u) * 3 + 0];
    float y = dR[(base + u) * 3 + 1];
    float z = dR[(base + u) * 3 + 2];
    int   nb = neigh[base + u];
    float Rij = x * x + y * y + z * z;          // squared distance (ref quirk)
    bool  mask = nb > 0;
    bool  mask_min = Rij < RMINF;
    float safe = (Rij > 0.f) ? Rij : 1.f;
    float s_inv = 1.f / safe;
    float s_cos = 0.5f * cosf((Rij - RMINF) * PI_OVER_DR) + 0.5f;
    float S = (mask && mask_min) ? s_inv
            : ((!mask_min && Rij < RMAXF) ? s_cos : 0.f);

    unsigned long long bal = __ballot(mask);
    if (t < 128 && (t & 63) == 0) balls[t >> 6] = bal;

    // ---- layers 1-2 (j split 24/26 across halves), t-values kept fp32 ----
    float tv[26];
    const int nj = half ? 26 : 24;
    const int jb = half ? 24 : 0;
    {
        float h[26];
        #pragma unroll
        for (int j = 0; j < 26; ++j) h[j] = (j < nj) ? be1[jb + j] : 0.f;
        for (int k = 0; k < 25; ++k) {
            float h1k = fast_tanh(fmaf(S, We0[k], be0[k]));
            const float* w = We1 + k * 50 + jb;
            #pragma unroll
            for (int j = 0; j < 26; ++j)
                if (j < nj) h[j] = fmaf(h1k, w[j], h[j]);
        }
        #pragma unroll
        for (int j = 0; j < 26; ++j) tv[j] = (j < nj) ? fast_tanh(h[j]) : 0.f;
    }

    // ---- write h2 HI plane (+ zero K-pad by half1) ----
    #pragma unroll
    for (int i = 0; i < 13; ++i) {
        if (2 * i < nj) {
            uint32_t pk = pack2(bf16_of(tv[2 * i]), bf16_of(tv[2 * i + 1]));
            uint32_t off = (uint32_t)(u * 128 + (jb + 2 * i) * 2) ^ ((u & 7) << 4);
            *(uint32_t*)(h2s + off) = pk;
        }
    }
    if (half) {
        #pragma unroll
        for (int i = 0; i < 7; ++i) {
            uint32_t off = (uint32_t)(u * 128 + (50 + 2 * i) * 2) ^ ((u & 7) << 4);
            *(uint32_t*)(h2s + off) = 0u;
        }
    }
    __syncthreads();   // #1: balls + h2 hi plane

    unsigned long long nb0 = ~balls[0], nb1 = ~balls[1];
    int firstBad;
    if (nb0)       firstBad = __ffsll((long long)nb0) - 1;
    else if (nb1)  firstBad = 64 + __ffsll((long long)nb1) - 1;
    else           firstBad = 128;
    if (half == 0) {
        float f = (u < firstBad) ? (S * s_inv) : 0.f;
        RiSh[u] = make_float4(S, f * x, f * y, f * z);
    }

    // ---- load A-frags HI ----
    const int m0 = wid * 32;
    const int ar = lane & 15;
    const int kg = lane >> 4;

    short8v ahi[2][2], alo[2][2];
    #pragma unroll
    for (int m = 0; m < 2; ++m)
        #pragma unroll
        for (int ks = 0; ks < 2; ++ks) {
            int row = m0 + m * 16 + ar;
            uint32_t off = (uint32_t)(row * 128 + ks * 64 + kg * 16) ^ ((row & 7) << 4);
            ahi[m][ks] = *(const short8v*)(h2s + off);
        }
    __syncthreads();   // #2: all hi-frag reads done

    // ---- write h2 LO plane (residuals) ----
    #pragma unroll
    for (int i = 0; i < 13; ++i) {
        if (2 * i < nj) {
            float a = tv[2 * i],     ra = a - bf16_to_f(bf16_of(a));
            float b = tv[2 * i + 1], rb = b - bf16_to_f(bf16_of(b));
            uint32_t pk = pack2(bf16_of(ra), bf16_of(rb));
            uint32_t off = (uint32_t)(u * 128 + (jb + 2 * i) * 2) ^ ((u & 7) << 4);
            *(uint32_t*)(h2s + off) = pk;
        }
    }
    if (half) {
        #pragma unroll
        for (int i = 0; i < 7; ++i) {
            uint32_t off = (uint32_t)(u * 128 + (50 + 2 * i) * 2) ^ ((u & 7) << 4);
            *(uint32_t*)(h2s + off) = 0u;
        }
    }
    __syncthreads();   // #3: lo plane ready

    #pragma unroll
    for (int m = 0; m < 2; ++m)
        #pragma unroll
        for (int ks = 0; ks < 2; ++ks) {
            int row = m0 + m * 16 + ar;
            uint32_t off = (uint32_t)(row * 128 + ks * 64 + kg * 16) ^ ((row & 7) << 4);
            alo[m][ks] = *(const short8v*)(h2s + off);
        }

    // ---- MFMA: acc = h_hi*W_hi + h_hi*W_lo + h_lo*W_hi ----
    // B-frags direct from global We2Hi/We2Lo [112][64] (L1-resident).
    f32x4 acc[2][7];
    #pragma unroll
    for (int m = 0; m < 2; ++m)
        #pragma unroll
        for (int n = 0; n < 7; ++n) acc[m][n] = (f32x4){0.f, 0.f, 0.f, 0.f};

    #pragma unroll
    for (int n = 0; n < 7; ++n) {
        int col = n * 16 + ar;
        short8v bhi[2], blo[2];
        #pragma unroll
        for (int ks = 0; ks < 2; ++ks) {
            size_t goff = (size_t)col * 64 + ks * 32 + kg * 8;
            bhi[ks] = *(const short8v*)(We2Hi + goff);
            blo[ks] = *(const short8v*)(We2Lo + goff);
        }
        #pragma unroll
        for (int m = 0; m < 2; ++m) {
            acc[m][n] = __builtin_amdgcn_mfma_f32_16x16x32_bf16(ahi[m][0], bhi[0], acc[m][n], 0, 0, 0);
            acc[m][n] = __builtin_amdgcn_mfma_f32_16x16x32_bf16(ahi[m][1], bhi[1], acc[m][n], 0, 0, 0);
            acc[m][n] = __builtin_amdgcn_mfma_f32_16x16x32_bf16(ahi[m][0], blo[0], acc[m][n], 0, 0, 0);
            acc[m][n] = __builtin_amdgcn_mfma_f32_16x16x32_bf16(ahi[m][1], blo[1], acc[m][n], 0, 0, 0);
            acc[m][n] = __builtin_amdgcn_mfma_f32_16x16x32_bf16(alo[m][0], bhi[0], acc[m][n], 0, 0, 0);
            acc[m][n] = __builtin_amdgcn_mfma_f32_16x16x32_bf16(alo[m][1], bhi[1], acc[m][n], 0, 0, 0);
        }
    }

    // ---- G = tanh(acc+bias) in fp32 regs; per-lane partial tmpB ----
    float4 riv[2][4];
    #pragma unroll
    for (int m = 0; m < 2; ++m)
        #pragma unroll
        for (int r = 0; r < 4; ++r)
            riv[m][r] = RiSh[m0 + m * 16 + kg * 4 + r];

    float P[4][7];
    #pragma unroll
    for (int c = 0; c < 4; ++c)
        #pragma unroll
        for (int n = 0; n < 7; ++n) P[c][n] = 0.f;

    #pragma unroll
    for (int n = 0; n < 7; ++n) {
        int col = n * 16 + ar;
        float bias = (col < 100) ? be2[col] : 0.f;
        #pragma unroll
        for (int m = 0; m < 2; ++m) {
            #pragma unroll
            for (int r = 0; r < 4; ++r) {
                float g = fast_tanh(acc[m][n][r] + bias);
                float4 ri = riv[m][r];
                P[0][n] = fmaf(ri.x, g, P[0][n]);
                P[1][n] = fmaf(ri.y, g, P[1][n]);
                P[2][n] = fmaf(ri.z, g, P[2][n]);
                P[3][n] = fmaf(ri.w, g, P[3][n]);
            }
        }
    }

    #pragma unroll
    for (int c = 0; c < 4; ++c)
        #pragma unroll
        for (int n = 0; n < 7; ++n) {
            P[c][n] += __shfl_xor(P[c][n], 16, 64);
            P[c][n] += __shfl_xor(P[c][n], 32, 64);
        }

    __syncthreads();   // #4: all LDS reads done; smem becomes tmpPart

    #pragma unroll
    for (int c = 0; c < 4; ++c) {
        if (kg == c) {
            #pragma unroll
            for (int n = 0; n < 7; ++n)
                tmpPart[(wid * 4 + c) * 128 + n * 16 + ar] = P[c][n];
        }
    }
    __syncthreads();   // #5

    for (int idx = t; idx < 512; idx += 256) {
        int c = idx >> 7, col = idx & 127;
        tmpBf[c][col] = tmpPart[(0 * 4 + c) * 128 + col]
                      + tmpPart[(1 * 4 + c) * 128 + col]
                      + tmpPart[(2 * 4 + c) * 128 + col]
                      + tmpPart[(3 * 4 + c) * 128 + col];
    }
    __syncthreads();   // #6

    // ---- phase 3: DR[i][M] -> bf16 hi/lo planes; i split by half ----
    if (u < 100) {
        float b0 = tmpBf[0][u];
        float b1 = tmpBf[1][u];
        float b2 = tmpBf[2][u];
        float b3 = tmpBf[3][u];
        uint16_t* dh = DRhi + (size_t)atom * 1600;
        uint16_t* dl = DRlo + (size_t)atom * 1600;
        const int i0 = half * 8;
        #pragma unroll
        for (int ii = 0; ii < 8; ++ii) {
            int i = i0 + ii;
            float v = tmpBf[0][i] * b0 + tmpBf[1][i] * b1
                    + tmpBf[2][i] * b2 + tmpBf[3][i] * b3;
            uint16_t hi = bf16_of(v);
            dh[i * 100 + u] = hi;
            dl[i * 100 + u] = bf16_of(v - bf16_to_f(hi));
        }
    }
}

// ---------------------------------------------------------------------------
// Fitting GEMM via split-bf16 MFMA, LDS-free (frags direct from global/L2).
// O[8192][256] = tanh(A[8192][KP] @ Wt^T + bias) as bf16 hi/lo planes.
// Grid (128, 2); 512 threads = 8 waves = 2 m-groups x 4 n-groups; BM=64 BN=128.
// ---------------------------------------------------------------------------
template<int KP>
__global__ __launch_bounds__(512, 4) void gemm_mfma_tanh(
    const uint16_t* __restrict__ Ahi, const uint16_t* __restrict__ Alo,
    const uint16_t* __restrict__ Wthi, const uint16_t* __restrict__ Wtlo,
    const float* __restrict__ bias,
    uint16_t* __restrict__ Ohi, uint16_t* __restrict__ Olo)
{
    const int tid = threadIdx.x;
    const int wid = tid >> 6, lane = tid & 63;
    const int mg = wid >> 2, ng = wid & 3;
    const int ar = lane & 15, kg = lane >> 4;
    const int row0 = blockIdx.x * 64 + mg * 32;
    const int col0 = blockIdx.y * 128 + ng * 32;

    f32x4 acc[2][2];
    #pragma unroll
    for (int m = 0; m < 2; ++m)
        #pragma unroll
        for (int n = 0; n < 2; ++n) acc[m][n] = (f32x4){0.f, 0.f, 0.f, 0.f};

    size_t abase[2], bbase[2];
    #pragma unroll
    for (int m = 0; m < 2; ++m) abase[m] = (size_t)(row0 + m * 16 + ar) * KP + kg * 8;
    #pragma unroll
    for (int n = 0; n < 2; ++n) bbase[n] = (size_t)(col0 + n * 16 + ar) * KP + kg * 8;

    #pragma unroll 2
    for (int k0 = 0; k0 < KP; k0 += 32) {
        short8v ah[2], al[2], bh[2], bl[2];
        #pragma unroll
        for (int m = 0; m < 2; ++m) {
            ah[m] = *(const short8v*)(Ahi + abase[m] + k0);
            al[m] = *(const short8v*)(Alo + abase[m] + k0);
        }
        #pragma unroll
        for (int n = 0; n < 2; ++n) {
            bh[n] = *(const short8v*)(Wthi + bbase[n] + k0);
            bl[n] = *(const short8v*)(Wtlo + bbase[n] + k0);
        }
        #pragma unroll
        for (int m = 0; m < 2; ++m)
            #pragma unroll
            for (int n = 0; n < 2; ++n) {
                acc[m][n] = __builtin_amdgcn_mfma_f32_16x16x32_bf16(ah[m], bh[n], acc[m][n], 0, 0, 0);
                acc[m][n] = __builtin_amdgcn_mfma_f32_16x16x32_bf16(ah[m], bl[n], acc[m][n], 0, 0, 0);
                acc[m][n] = __builtin_amdgcn_mfma_f32_16x16x32_bf16(al[m], bh[n], acc[m][n], 0, 0, 0);
            }
    }

    // epilogue: D row = m*16 + kg*4 + r, col = n*16 + ar
    #pragma unroll
    for (int n = 0; n < 2; ++n) {
        int col = col0 + n * 16 + ar;
        bool valid = col < 240;
        float bv = valid ? bias[col] : 0.f;
        #pragma unroll
        for (int m = 0; m < 2; ++m) {
            #pragma unroll
            for (int r = 0; r < 4; ++r) {
                int row = row0 + m * 16 + kg * 4 + r;
                float v = valid ? fast_tanh(acc[m][n][r] + bv) : 0.f;
                uint16_t hi = bf16_of(v);
                Ohi[(size_t)row * 256 + col] = hi;
                Olo[(size_t)row * 256 + col] = bf16_of(v - bf16_to_f(hi));
            }
        }
    }
}

// ---------------------------------------------------------------------------
// Ei = (h_hi+h_lo) @ Wf3 + bf3 : one wave per atom, shuffle reduce.
// ---------------------------------------------------------------------------
__global__ __launch_bounds__(256) void final_dot_kernel(
    const uint16_t* __restrict__ Hhi, const uint16_t* __restrict__ Hlo,
    const float* __restrict__ Wf3, const float* __restrict__ bf3,
    float* __restrict__ out)
{
    int wave = threadIdx.x >> 6, lane = threadIdx.x & 63;
    int atom = blockIdx.x * 4 + wave;
    float v = 0.f;
    if (lane < 60) {
        const uint16_t* ph = Hhi + (size_t)atom * 256 + lane * 4;
        const uint16_t* pl = Hlo + (size_t)atom * 256 + lane * 4;
        ushort4 h4 = *(const ushort4*)ph;
        ushort4 l4 = *(const ushort4*)pl;
        float4 w = *(const float4*)&Wf3[lane * 4];
        v = (bf16_to_f(h4.x) + bf16_to_f(l4.x)) * w.x
          + (bf16_to_f(h4.y) + bf16_to_f(l4.y)) * w.y
          + (bf16_to_f(h4.z) + bf16_to_f(l4.z)) * w.z
          + (bf16_to_f(h4.w) + bf16_to_f(l4.w)) * w.w;
    }
    #pragma unroll
    for (int off = 32; off; off >>= 1) v += __shfl_down(v, off, 64);
    if (lane == 0) out[4 + atom] = v + bf3[0];
}

__global__ __launch_bounds__(256) void etot_kernel(float* __restrict__ out)
{
    __shared__ float red[256];
    int b = blockIdx.x, t = threadIdx.x;
    float s = 0.f;
    for (int i = t; i < NN; i += 256) s += out[4 + b * NN + i];
    red[t] = s;
    __syncthreads();
    for (int w = 128; w; w >>= 1) {
        if (t < w) red[t] += red[t + w];
        __syncthreads();
    }
    if (t == 0) out[b] = red[0];
}

// ---------------------------------------------------------------------------
extern "C" void kernel_launch(void* const* d_in, const int* in_sizes, int n_in,
                              void* d_out, int out_size, void* d_ws, size_t ws_size,
                              hipStream_t stream)
{
    const float* dR    = (const float*)d_in[0];
    const int*   neigh = (const int*)d_in[1];
    const float* We0   = (const float*)d_in[2];
    const float* be0   = (const float*)d_in[3];
    const float* We1   = (const float*)d_in[4];
    const float* be1   = (const float*)d_in[5];
    const float* We2   = (const float*)d_in[6];
    const float* be2   = (const float*)d_in[7];
    const float* Wf0   = (const float*)d_in[8];
    const float* bf0   = (const float*)d_in[9];
    const float* Wf1   = (const float*)d_in[10];
    const float* bf1   = (const float*)d_in[11];
    const float* Wf2   = (const float*)d_in[12];
    const float* bf2   = (const float*)d_in[13];
    const float* Wf3   = (const float*)d_in[14];
    const float* bf3   = (const float*)d_in[15];
    float* out = (float*)d_out;

    char* ws = (char*)d_ws;
    uint16_t* We2HiB = (uint16_t*)(ws + 0);                   // 14336 B
    uint16_t* We2LoB = (uint16_t*)(ws + 14336);               // 14336 B
    uint16_t* Wt0hi  = (uint16_t*)(ws + 32768);               // 256*1600*2 = 819200
    uint16_t* Wt0lo  = (uint16_t*)(ws + 851968);              // 819200
    uint16_t* Wt1hi  = (uint16_t*)(ws + 1671168);             // 131072
    uint16_t* Wt1lo  = (uint16_t*)(ws + 1802240);             // 131072
    uint16_t* Wt2hi  = (uint16_t*)(ws + 1933312);             // 131072
    uint16_t* Wt2lo  = (uint16_t*)(ws + 2064384);             // 131072
    uint16_t* DRhi   = (uint16_t*)(ws + 2195456);             // 26214400
    uint16_t* DRlo   = (uint16_t*)(ws + 28409856);            // 26214400
    uint16_t* hAhi   = (uint16_t*)(ws + 54624256);            // 4194304
    uint16_t* hAlo   = (uint16_t*)(ws + 58818560);            // 4194304
    uint16_t* hBhi   = (uint16_t*)(ws + 63012864);            // 4194304
    uint16_t* hBlo   = (uint16_t*)(ws + 67207168);            // 4194304
                                                              // end 71401472

    prep_kernel<<<28, 256, 0, stream>>>(We2, We2HiB, We2LoB);
    prep_wt_kernel<<<1600, 256, 0, stream>>>(Wf0, Wt0hi, Wt0lo, 1600, 1600);
    prep_wt_kernel<<<256, 256, 0, stream>>>(Wf1, Wt1hi, Wt1lo, 240, 256);
    prep_wt_kernel<<<256, 256, 0, stream>>>(Wf2, Wt2hi, Wt2lo, 240, 256);

    embed_kernel<<<NB * NN, 256, 0, stream>>>(dR, neigh, We0, be0, We1, be1,
                                              We2HiB, We2LoB, be2, DRhi, DRlo);

    gemm_mfma_tanh<1600><<<dim3(128, 2), 512, 0, stream>>>(DRhi, DRlo, Wt0hi, Wt0lo, bf0, hAhi, hAlo);
    gemm_mfma_tanh<256><<<dim3(128, 2), 512, 0, stream>>>(hAhi, hAlo, Wt1hi, Wt1lo, bf1, hBhi, hBlo);
    gemm_mfma_tanh<256><<<dim3(128, 2), 512, 0, stream>>>(hBhi, hBlo, Wt2hi, Wt2lo, bf2, hAhi, hAlo);

    final_dot_kernel<<<NB * NN / 4, 256, 0, stream>>>(hAhi, hAlo, Wf3, bf3, out);
    etot_kernel<<<NB, 256, 0, stream>>>(out);
}

// Round 7
// 440.905 us; speedup vs baseline: 1.0867x; 1.0867x over previous
//
#include <hip/hip_runtime.h>
#include <hip/hip_bf16.h>
#include <math.h>
#include <stdint.h>

#define NB 4
#define NN 2048
#define NA 128
#define RMINF 5.8f
#define RMAXF 6.0f
#define PI_OVER_DR 15.707963267948966f  /* pi / (RMAX-RMIN) */

typedef __attribute__((ext_vector_type(8))) short short8v;   // 8 bf16 (MFMA A/B frag)
typedef __attribute__((ext_vector_type(4))) float f32x4;     // MFMA C/D frag

// Exact tanh via exp: tanh(x) = 1 - 2/(e^{2x}+1). ~7 VALU inst, rel err ~1e-6.
__device__ __forceinline__ float fast_tanh(float x)
{
    x = fminf(fmaxf(x, -15.f), 15.f);
    float e = __expf(2.f * x);
    float r = __builtin_amdgcn_rcpf(e + 1.f);
    return fmaf(-2.f, r, 1.f);
}

__device__ __forceinline__ uint16_t bf16_of(float x)
{
    __hip_bfloat16 b = __float2bfloat16(x);
    return *(uint16_t*)&b;
}

__device__ __forceinline__ float bf16_to_f(uint16_t v)
{
    union { uint32_t u; float f; } c; c.u = ((uint32_t)v) << 16; return c.f;
}

__device__ __forceinline__ uint32_t pack2(uint16_t lo, uint16_t hi)
{
    return (uint32_t)lo | ((uint32_t)hi << 16);
}

// ---------------------------------------------------------------------------
// Prep 1: We2 [50][100] fp32 -> We2Hi/We2Lo [112][64] bf16 (transposed, padded).
// ---------------------------------------------------------------------------
__global__ void prep_kernel(const float* __restrict__ We2,
                            uint16_t* __restrict__ We2Hi,
                            uint16_t* __restrict__ We2Lo)
{
    int idx = blockIdx.x * 256 + threadIdx.x;
    if (idx < 112 * 64) {
        int j = idx >> 6, k = idx & 63;
        float v = (j < 100 && k < 50) ? We2[k * 100 + j] : 0.f;
        uint16_t hi = bf16_of(v);
        We2Hi[idx] = hi;
        We2Lo[idx] = bf16_of(v - bf16_to_f(hi));
    }
}

// ---------------------------------------------------------------------------
// Prep 2: fitting weight W [K][240] fp32 -> Wt hi/lo [256][KP] bf16
// (transposed, zero-padded in both N (240->256) and K (K->KP)).
// ---------------------------------------------------------------------------
__global__ void prep_wt_kernel(const float* __restrict__ W,
                               uint16_t* __restrict__ Whi,
                               uint16_t* __restrict__ Wlo,
                               int K, int KP)
{
    int idx = blockIdx.x * 256 + threadIdx.x;
    if (idx < 256 * KP) {
        int colN = idx / KP, k = idx - colN * KP;
        float v = (colN < 240 && k < K) ? W[k * 240 + colN] : 0.f;
        uint16_t hi = bf16_of(v);
        Whi[idx] = hi;
        Wlo[idx] = bf16_of(v - bf16_to_f(hi));
    }
}

// ---------------------------------------------------------------------------
// Per-atom kernel v7: == v6 but __launch_bounds__(256,4).
// v6's (256,6) forced a <=64-VGPR cap (HW quantum) -> massive scratch spill
// (FETCH 218MB / WRITE 524MB). (256,4) caps at 128: natural ~68-100 VGPR,
// no spill; occupancy 4 waves/SIMD = 50% (VGPR-quantum-bound).
// ---------------------------------------------------------------------------
__global__ __launch_bounds__(256, 4) void embed_kernel(
    const float* __restrict__ dR, const int* __restrict__ neigh,
    const float* __restrict__ We0, const float* __restrict__ be0,
    const float* __restrict__ We1, const float* __restrict__ be1,
    const uint16_t* __restrict__ We2Hi, const uint16_t* __restrict__ We2Lo,
    const float* __restrict__ be2,
    uint16_t* __restrict__ DRhi, uint16_t* __restrict__ DRlo)
{
    const int atom = blockIdx.x;
    const int t = threadIdx.x;
    const int half = t >> 7;
    const int u = t & 127;          // neighbor index
    const int lane = t & 63;
    const int wid = t >> 6;

    __shared__ __align__(16) char smem[16384];
    __shared__ float4 RiSh[128];
    __shared__ float  tmpBf[4][128];
    __shared__ unsigned long long balls[2];

    char* h2s = smem;               // [128]x128B bf16, XOR-swizzled (hi, then lo)
    float* tmpPart = (float*)smem;  // after MFMA: [4 waves][4 c][128 col] f32

    // ---- phase 0: S_Rij, mask, ballot ----
    const int base = atom * NA;
    float x = dR[(base + u) * 3 + 0];
    float y = dR[(base + u) * 3 + 1];
    float z = dR[(base + u) * 3 + 2];
    int   nb = neigh[base + u];
    float Rij = x * x + y * y + z * z;          // squared distance (ref quirk)
    bool  mask = nb > 0;
    bool  mask_min = Rij < RMINF;
    float safe = (Rij > 0.f) ? Rij : 1.f;
    float s_inv = 1.f / safe;
    float s_cos = 0.5f * cosf((Rij - RMINF) * PI_OVER_DR) + 0.5f;
    float S = (mask && mask_min) ? s_inv
            : ((!mask_min && Rij < RMAXF) ? s_cos : 0.f);

    unsigned long long bal = __ballot(mask);
    if (t < 128 && (t & 63) == 0) balls[t >> 6] = bal;

    // ---- layers 1-2 (j split 24/26 across halves), t-values kept fp32 ----
    float tv[26];
    const int nj = half ? 26 : 24;
    const int jb = half ? 24 : 0;
    {
        float h[26];
        #pragma unroll
        for (int j = 0; j < 26; ++j) h[j] = (j < nj) ? be1[jb + j] : 0.f;
        for (int k = 0; k < 25; ++k) {
            float h1k = fast_tanh(fmaf(S, We0[k], be0[k]));
            const float* w = We1 + k * 50 + jb;
            #pragma unroll
            for (int j = 0; j < 26; ++j)
                if (j < nj) h[j] = fmaf(h1k, w[j], h[j]);
        }
        #pragma unroll
        for (int j = 0; j < 26; ++j) tv[j] = (j < nj) ? fast_tanh(h[j]) : 0.f;
    }

    // ---- write h2 HI plane (+ zero K-pad by half1) ----
    #pragma unroll
    for (int i = 0; i < 13; ++i) {
        if (2 * i < nj) {
            uint32_t pk = pack2(bf16_of(tv[2 * i]), bf16_of(tv[2 * i + 1]));
            uint32_t off = (uint32_t)(u * 128 + (jb + 2 * i) * 2) ^ ((u & 7) << 4);
            *(uint32_t*)(h2s + off) = pk;
        }
    }
    if (half) {
        #pragma unroll
        for (int i = 0; i < 7; ++i) {
            uint32_t off = (uint32_t)(u * 128 + (50 + 2 * i) * 2) ^ ((u & 7) << 4);
            *(uint32_t*)(h2s + off) = 0u;
        }
    }
    __syncthreads();   // #1: balls + h2 hi plane

    unsigned long long nb0 = ~balls[0], nb1 = ~balls[1];
    int firstBad;
    if (nb0)       firstBad = __ffsll((long long)nb0) - 1;
    else if (nb1)  firstBad = 64 + __ffsll((long long)nb1) - 1;
    else           firstBad = 128;
    if (half == 0) {
        float f = (u < firstBad) ? (S * s_inv) : 0.f;
        RiSh[u] = make_float4(S, f * x, f * y, f * z);
    }

    // ---- load A-frags HI ----
    const int m0 = wid * 32;
    const int ar = lane & 15;
    const int kg = lane >> 4;

    short8v ahi[2][2], alo[2][2];
    #pragma unroll
    for (int m = 0; m < 2; ++m)
        #pragma unroll
        for (int ks = 0; ks < 2; ++ks) {
            int row = m0 + m * 16 + ar;
            uint32_t off = (uint32_t)(row * 128 + ks * 64 + kg * 16) ^ ((row & 7) << 4);
            ahi[m][ks] = *(const short8v*)(h2s + off);
        }
    __syncthreads();   // #2: all hi-frag reads done

    // ---- write h2 LO plane (residuals) ----
    #pragma unroll
    for (int i = 0; i < 13; ++i) {
        if (2 * i < nj) {
            float a = tv[2 * i],     ra = a - bf16_to_f(bf16_of(a));
            float b = tv[2 * i + 1], rb = b - bf16_to_f(bf16_of(b));
            uint32_t pk = pack2(bf16_of(ra), bf16_of(rb));
            uint32_t off = (uint32_t)(u * 128 + (jb + 2 * i) * 2) ^ ((u & 7) << 4);
            *(uint32_t*)(h2s + off) = pk;
        }
    }
    if (half) {
        #pragma unroll
        for (int i = 0; i < 7; ++i) {
            uint32_t off = (uint32_t)(u * 128 + (50 + 2 * i) * 2) ^ ((u & 7) << 4);
            *(uint32_t*)(h2s + off) = 0u;
        }
    }
    __syncthreads();   // #3: lo plane ready

    #pragma unroll
    for (int m = 0; m < 2; ++m)
        #pragma unroll
        for (int ks = 0; ks < 2; ++ks) {
            int row = m0 + m * 16 + ar;
            uint32_t off = (uint32_t)(row * 128 + ks * 64 + kg * 16) ^ ((row & 7) << 4);
            alo[m][ks] = *(const short8v*)(h2s + off);
        }

    // ---- MFMA: acc = h_hi*W_hi + h_hi*W_lo + h_lo*W_hi ----
    // B-frags direct from global We2Hi/We2Lo [112][64] (L1-resident).
    f32x4 acc[2][7];
    #pragma unroll
    for (int m = 0; m < 2; ++m)
        #pragma unroll
        for (int n = 0; n < 7; ++n) acc[m][n] = (f32x4){0.f, 0.f, 0.f, 0.f};

    #pragma unroll
    for (int n = 0; n < 7; ++n) {
        int col = n * 16 + ar;
        short8v bhi[2], blo[2];
        #pragma unroll
        for (int ks = 0; ks < 2; ++ks) {
            size_t goff = (size_t)col * 64 + ks * 32 + kg * 8;
            bhi[ks] = *(const short8v*)(We2Hi + goff);
            blo[ks] = *(const short8v*)(We2Lo + goff);
        }
        #pragma unroll
        for (int m = 0; m < 2; ++m) {
            acc[m][n] = __builtin_amdgcn_mfma_f32_16x16x32_bf16(ahi[m][0], bhi[0], acc[m][n], 0, 0, 0);
            acc[m][n] = __builtin_amdgcn_mfma_f32_16x16x32_bf16(ahi[m][1], bhi[1], acc[m][n], 0, 0, 0);
            acc[m][n] = __builtin_amdgcn_mfma_f32_16x16x32_bf16(ahi[m][0], blo[0], acc[m][n], 0, 0, 0);
            acc[m][n] = __builtin_amdgcn_mfma_f32_16x16x32_bf16(ahi[m][1], blo[1], acc[m][n], 0, 0, 0);
            acc[m][n] = __builtin_amdgcn_mfma_f32_16x16x32_bf16(alo[m][0], bhi[0], acc[m][n], 0, 0, 0);
            acc[m][n] = __builtin_amdgcn_mfma_f32_16x16x32_bf16(alo[m][1], bhi[1], acc[m][n], 0, 0, 0);
        }
    }

    // ---- G = tanh(acc+bias) in fp32 regs; per-lane partial tmpB ----
    float4 riv[2][4];
    #pragma unroll
    for (int m = 0; m < 2; ++m)
        #pragma unroll
        for (int r = 0; r < 4; ++r)
            riv[m][r] = RiSh[m0 + m * 16 + kg * 4 + r];

    float P[4][7];
    #pragma unroll
    for (int c = 0; c < 4; ++c)
        #pragma unroll
        for (int n = 0; n < 7; ++n) P[c][n] = 0.f;

    #pragma unroll
    for (int n = 0; n < 7; ++n) {
        int col = n * 16 + ar;
        float bias = (col < 100) ? be2[col] : 0.f;
        #pragma unroll
        for (int m = 0; m < 2; ++m) {
            #pragma unroll
            for (int r = 0; r < 4; ++r) {
                float g = fast_tanh(acc[m][n][r] + bias);
                float4 ri = riv[m][r];
                P[0][n] = fmaf(ri.x, g, P[0][n]);
                P[1][n] = fmaf(ri.y, g, P[1][n]);
                P[2][n] = fmaf(ri.z, g, P[2][n]);
                P[3][n] = fmaf(ri.w, g, P[3][n]);
            }
        }
    }

    #pragma unroll
    for (int c = 0; c < 4; ++c)
        #pragma unroll
        for (int n = 0; n < 7; ++n) {
            P[c][n] += __shfl_xor(P[c][n], 16, 64);
            P[c][n] += __shfl_xor(P[c][n], 32, 64);
        }

    __syncthreads();   // #4: all LDS reads done; smem becomes tmpPart

    #pragma unroll
    for (int c = 0; c < 4; ++c) {
        if (kg == c) {
            #pragma unroll
            for (int n = 0; n < 7; ++n)
                tmpPart[(wid * 4 + c) * 128 + n * 16 + ar] = P[c][n];
        }
    }
    __syncthreads();   // #5

    for (int idx = t; idx < 512; idx += 256) {
        int c = idx >> 7, col = idx & 127;
        tmpBf[c][col] = tmpPart[(0 * 4 + c) * 128 + col]
                      + tmpPart[(1 * 4 + c) * 128 + col]
                      + tmpPart[(2 * 4 + c) * 128 + col]
                      + tmpPart[(3 * 4 + c) * 128 + col];
    }
    __syncthreads();   // #6

    // ---- phase 3: DR[i][M] -> bf16 hi/lo planes; i split by half ----
    if (u < 100) {
        float b0 = tmpBf[0][u];
        float b1 = tmpBf[1][u];
        float b2 = tmpBf[2][u];
        float b3 = tmpBf[3][u];
        uint16_t* dh = DRhi + (size_t)atom * 1600;
        uint16_t* dl = DRlo + (size_t)atom * 1600;
        const int i0 = half * 8;
        #pragma unroll
        for (int ii = 0; ii < 8; ++ii) {
            int i = i0 + ii;
            float v = tmpBf[0][i] * b0 + tmpBf[1][i] * b1
                    + tmpBf[2][i] * b2 + tmpBf[3][i] * b3;
            uint16_t hi = bf16_of(v);
            dh[i * 100 + u] = hi;
            dl[i * 100 + u] = bf16_of(v - bf16_to_f(hi));
        }
    }
}

// ---------------------------------------------------------------------------
// Fitting GEMM via split-bf16 MFMA, LDS-free (frags direct from global/L2).
// O[8192][256] = tanh(A[8192][KP] @ Wt^T + bias) as bf16 hi/lo planes.
// Grid (128, 2); 512 threads = 8 waves = 2 m-groups x 4 n-groups; BM=64 BN=128.
// ---------------------------------------------------------------------------
template<int KP>
__global__ __launch_bounds__(512, 4) void gemm_mfma_tanh(
    const uint16_t* __restrict__ Ahi, const uint16_t* __restrict__ Alo,
    const uint16_t* __restrict__ Wthi, const uint16_t* __restrict__ Wtlo,
    const float* __restrict__ bias,
    uint16_t* __restrict__ Ohi, uint16_t* __restrict__ Olo)
{
    const int tid = threadIdx.x;
    const int wid = tid >> 6, lane = tid & 63;
    const int mg = wid >> 2, ng = wid & 3;
    const int ar = lane & 15, kg = lane >> 4;
    const int row0 = blockIdx.x * 64 + mg * 32;
    const int col0 = blockIdx.y * 128 + ng * 32;

    f32x4 acc[2][2];
    #pragma unroll
    for (int m = 0; m < 2; ++m)
        #pragma unroll
        for (int n = 0; n < 2; ++n) acc[m][n] = (f32x4){0.f, 0.f, 0.f, 0.f};

    size_t abase[2], bbase[2];
    #pragma unroll
    for (int m = 0; m < 2; ++m) abase[m] = (size_t)(row0 + m * 16 + ar) * KP + kg * 8;
    #pragma unroll
    for (int n = 0; n < 2; ++n) bbase[n] = (size_t)(col0 + n * 16 + ar) * KP + kg * 8;

    #pragma unroll 2
    for (int k0 = 0; k0 < KP; k0 += 32) {
        short8v ah[2], al[2], bh[2], bl[2];
        #pragma unroll
        for (int m = 0; m < 2; ++m) {
            ah[m] = *(const short8v*)(Ahi + abase[m] + k0);
            al[m] = *(const short8v*)(Alo + abase[m] + k0);
        }
        #pragma unroll
        for (int n = 0; n < 2; ++n) {
            bh[n] = *(const short8v*)(Wthi + bbase[n] + k0);
            bl[n] = *(const short8v*)(Wtlo + bbase[n] + k0);
        }
        #pragma unroll
        for (int m = 0; m < 2; ++m)
            #pragma unroll
            for (int n = 0; n < 2; ++n) {
                acc[m][n] = __builtin_amdgcn_mfma_f32_16x16x32_bf16(ah[m], bh[n], acc[m][n], 0, 0, 0);
                acc[m][n] = __builtin_amdgcn_mfma_f32_16x16x32_bf16(ah[m], bl[n], acc[m][n], 0, 0, 0);
                acc[m][n] = __builtin_amdgcn_mfma_f32_16x16x32_bf16(al[m], bh[n], acc[m][n], 0, 0, 0);
            }
    }

    // epilogue: D row = m*16 + kg*4 + r, col = n*16 + ar
    #pragma unroll
    for (int n = 0; n < 2; ++n) {
        int col = col0 + n * 16 + ar;
        bool valid = col < 240;
        float bv = valid ? bias[col] : 0.f;
        #pragma unroll
        for (int m = 0; m < 2; ++m) {
            #pragma unroll
            for (int r = 0; r < 4; ++r) {
                int row = row0 + m * 16 + kg * 4 + r;
                float v = valid ? fast_tanh(acc[m][n][r] + bv) : 0.f;
                uint16_t hi = bf16_of(v);
                Ohi[(size_t)row * 256 + col] = hi;
                Olo[(size_t)row * 256 + col] = bf16_of(v - bf16_to_f(hi));
            }
        }
    }
}

// ---------------------------------------------------------------------------
// Ei = (h_hi+h_lo) @ Wf3 + bf3 : one wave per atom, shuffle reduce.
// ---------------------------------------------------------------------------
__global__ __launch_bounds__(256) void final_dot_kernel(
    const uint16_t* __restrict__ Hhi, const uint16_t* __restrict__ Hlo,
    const float* __restrict__ Wf3, const float* __restrict__ bf3,
    float* __restrict__ out)
{
    int wave = threadIdx.x >> 6, lane = threadIdx.x & 63;
    int atom = blockIdx.x * 4 + wave;
    float v = 0.f;
    if (lane < 60) {
        const uint16_t* ph = Hhi + (size_t)atom * 256 + lane * 4;
        const uint16_t* pl = Hlo + (size_t)atom * 256 + lane * 4;
        ushort4 h4 = *(const ushort4*)ph;
        ushort4 l4 = *(const ushort4*)pl;
        float4 w = *(const float4*)&Wf3[lane * 4];
        v = (bf16_to_f(h4.x) + bf16_to_f(l4.x)) * w.x
          + (bf16_to_f(h4.y) + bf16_to_f(l4.y)) * w.y
          + (bf16_to_f(h4.z) + bf16_to_f(l4.z)) * w.z
          + (bf16_to_f(h4.w) + bf16_to_f(l4.w)) * w.w;
    }
    #pragma unroll
    for (int off = 32; off; off >>= 1) v += __shfl_down(v, off, 64);
    if (lane == 0) out[4 + atom] = v + bf3[0];
}

__global__ __launch_bounds__(256) void etot_kernel(float* __restrict__ out)
{
    __shared__ float red[256];
    int b = blockIdx.x, t = threadIdx.x;
    float s = 0.f;
    for (int i = t; i < NN; i += 256) s += out[4 + b * NN + i];
    red[t] = s;
    __syncthreads();
    for (int w = 128; w; w >>= 1) {
        if (t < w) red[t] += red[t + w];
        __syncthreads();
    }
    if (t == 0) out[b] = red[0];
}

// ---------------------------------------------------------------------------
extern "C" void kernel_launch(void* const* d_in, const int* in_sizes, int n_in,
                              void* d_out, int out_size, void* d_ws, size_t ws_size,
                              hipStream_t stream)
{
    const float* dR    = (const float*)d_in[0];
    const int*   neigh = (const int*)d_in[1];
    const float* We0   = (const float*)d_in[2];
    const float* be0   = (const float*)d_in[3];
    const float* We1   = (const float*)d_in[4];
    const float* be1   = (const float*)d_in[5];
    const float* We2   = (const float*)d_in[6];
    const float* be2   = (const float*)d_in[7];
    const float* Wf0   = (const float*)d_in[8];
    const float* bf0   = (const float*)d_in[9];
    const float* Wf1   = (const float*)d_in[10];
    const float* bf1   = (const float*)d_in[11];
    const float* Wf2   = (const float*)d_in[12];
    const float* bf2   = (const float*)d_in[13];
    const float* Wf3   = (const float*)d_in[14];
    const float* bf3   = (const float*)d_in[15];
    float* out = (float*)d_out;

    char* ws = (char*)d_ws;
    uint16_t* We2HiB = (uint16_t*)(ws + 0);                   // 14336 B
    uint16_t* We2LoB = (uint16_t*)(ws + 14336);               // 14336 B
    uint16_t* Wt0hi  = (uint16_t*)(ws + 32768);               // 256*1600*2 = 819200
    uint16_t* Wt0lo  = (uint16_t*)(ws + 851968);              // 819200
    uint16_t* Wt1hi  = (uint16_t*)(ws + 1671168);             // 131072
    uint16_t* Wt1lo  = (uint16_t*)(ws + 1802240);             // 131072
    uint16_t* Wt2hi  = (uint16_t*)(ws + 1933312);             // 131072
    uint16_t* Wt2lo  = (uint16_t*)(ws + 2064384);             // 131072
    uint16_t* DRhi   = (uint16_t*)(ws + 2195456);             // 26214400
    uint16_t* DRlo   = (uint16_t*)(ws + 28409856);            // 26214400
    uint16_t* hAhi   = (uint16_t*)(ws + 54624256);            // 4194304
    uint16_t* hAlo   = (uint16_t*)(ws + 58818560);            // 4194304
    uint16_t* hBhi   = (uint16_t*)(ws + 63012864);            // 4194304
    uint16_t* hBlo   = (uint16_t*)(ws + 67207168);            // 4194304
                                                              // end 71401472

    prep_kernel<<<28, 256, 0, stream>>>(We2, We2HiB, We2LoB);
    prep_wt_kernel<<<1600, 256, 0, stream>>>(Wf0, Wt0hi, Wt0lo, 1600, 1600);
    prep_wt_kernel<<<256, 256, 0, stream>>>(Wf1, Wt1hi, Wt1lo, 240, 256);
    prep_wt_kernel<<<256, 256, 0, stream>>>(Wf2, Wt2hi, Wt2lo, 240, 256);

    embed_kernel<<<NB * NN, 256, 0, stream>>>(dR, neigh, We0, be0, We1, be1,
                                              We2HiB, We2LoB, be2, DRhi, DRlo);

    gemm_mfma_tanh<1600><<<dim3(128, 2), 512, 0, stream>>>(DRhi, DRlo, Wt0hi, Wt0lo, bf0, hAhi, hAlo);
    gemm_mfma_tanh<256><<<dim3(128, 2), 512, 0, stream>>>(hAhi, hAlo, Wt1hi, Wt1lo, bf1, hBhi, hBlo);
    gemm_mfma_tanh<256><<<dim3(128, 2), 512, 0, stream>>>(hBhi, hBlo, Wt2hi, Wt2lo, bf2, hAhi, hAlo);

    final_dot_kernel<<<NB * NN / 4, 256, 0, stream>>>(hAhi, hAlo, Wf3, bf3, out);
    etot_kernel<<<NB, 256, 0, stream>>>(out);
}

// Round 8
// 248.735 us; speedup vs baseline: 1.9262x; 1.7726x over previous
//
#include <hip/hip_runtime.h>
#include <hip/hip_bf16.h>
#include <math.h>
#include <stdint.h>

#define NB 4
#define NN 2048
#define NA 128
#define NK 2048                         /* table intervals; knots 0..NK */
#define RMINF 5.8f
#define RMAXF 6.0f
#define PI_OVER_DR 15.707963267948966f  /* pi / (RMAX-RMIN) */

typedef __attribute__((ext_vector_type(8))) short short8v;   // 8 bf16 (MFMA A/B frag)
typedef __attribute__((ext_vector_type(4))) float f32x4;     // MFMA C/D frag

// Exact tanh via exp: tanh(x) = 1 - 2/(e^{2x}+1). ~7 VALU inst, rel err ~1e-6.
__device__ __forceinline__ float fast_tanh(float x)
{
    x = fminf(fmaxf(x, -15.f), 15.f);
    float e = __expf(2.f * x);
    float r = __builtin_amdgcn_rcpf(e + 1.f);
    return fmaf(-2.f, r, 1.f);
}

__device__ __forceinline__ uint16_t bf16_of(float x)
{
    __hip_bfloat16 b = __float2bfloat16(x);
    return *(uint16_t*)&b;
}

__device__ __forceinline__ float bf16_to_f(uint16_t v)
{
    union { uint32_t u; float f; } c; c.u = ((uint32_t)v) << 16; return c.f;
}

// ---------------------------------------------------------------------------
// Table build: TBL[knot][j] = G_j(S(knot)), knot = 0..NK, u = knot/NK,
// S = u/(1-u) (S=1e8 at u=1). 4 threads per knot (25 output channels each).
// Exact fp32 chain -> table error is lerp-only (~3e-4 worst case).
// ---------------------------------------------------------------------------
__global__ void prep_table_kernel(
    const float* __restrict__ We0, const float* __restrict__ be0,
    const float* __restrict__ We1, const float* __restrict__ be1,
    const float* __restrict__ We2, const float* __restrict__ be2,
    float* __restrict__ TBL)
{
    int idx = blockIdx.x * 256 + threadIdx.x;
    int knot = idx >> 2, q = idx & 3;
    if (knot > NK) return;
    float uu = (float)knot / (float)NK;
    float S = (knot == NK) ? 1e8f : uu / (1.f - uu);

    float h1[25];
    #pragma unroll
    for (int k = 0; k < 25; ++k) h1[k] = fast_tanh(fmaf(S, We0[k], be0[k]));

    float h2[50];
    #pragma unroll
    for (int j = 0; j < 50; ++j) h2[j] = be1[j];
    #pragma unroll
    for (int k = 0; k < 25; ++k) {
        float v = h1[k];
        #pragma unroll
        for (int j = 0; j < 50; ++j) h2[j] = fmaf(v, We1[k * 50 + j], h2[j]);
    }
    #pragma unroll
    for (int j = 0; j < 50; ++j) h2[j] = fast_tanh(h2[j]);

    for (int jj = 0; jj < 25; ++jj) {
        int j = q * 25 + jj;
        float acc = be2[j];
        #pragma unroll
        for (int k = 0; k < 50; ++k) acc = fmaf(h2[k], We2[k * 100 + j], acc);
        TBL[knot * 100 + j] = fast_tanh(acc);
    }
}

// ---------------------------------------------------------------------------
// Prep: fitting weight W [K][240] fp32 -> Wt hi/lo [256][KP] bf16
// (transposed, zero-padded in both N (240->256) and K (K->KP)).
// ---------------------------------------------------------------------------
__global__ void prep_wt_kernel(const float* __restrict__ W,
                               uint16_t* __restrict__ Whi,
                               uint16_t* __restrict__ Wlo,
                               int K, int KP)
{
    int idx = blockIdx.x * 256 + threadIdx.x;
    if (idx < 256 * KP) {
        int colN = idx / KP, k = idx - colN * KP;
        float v = (colN < 240 && k < K) ? W[k * 240 + colN] : 0.f;
        uint16_t hi = bf16_of(v);
        Whi[idx] = hi;
        Wlo[idx] = bf16_of(v - bf16_to_f(hi));
    }
}

// ---------------------------------------------------------------------------
// Descriptor kernel v8 (table-based): per atom, 256 threads = 2 halves.
//  phase0: S, prefix, Ri (half0) + table coords (half1)
//  phaseB: tmpB[c][j] = sum_a Ri[a][c] * lerp(TBL, S_a)[j]  (a split by half)
//  phaseC: DR = tmpB^T_16 x tmpB -> bf16 hi/lo planes
// LDS ~6.3 KB, no MFMA, no bank conflicts -> full occupancy.
// ---------------------------------------------------------------------------
__global__ __launch_bounds__(256) void desc_kernel(
    const float* __restrict__ dR, const int* __restrict__ neigh,
    const float* __restrict__ TBL,
    uint16_t* __restrict__ DRhi, uint16_t* __restrict__ DRlo)
{
    const int atom = blockIdx.x;
    const int t = threadIdx.x;
    const int half = t >> 7;
    const int u = t & 127;          // neighbor index (phase0/B j-channel)

    __shared__ float4 RiSh[128];
    __shared__ float2 IFSh[128];    // (frac, (float)knot_index)
    __shared__ float  tmpBSh[2][4][100];
    __shared__ unsigned long long balls[2];

    // ---- phase 0: S_Rij, mask, ballot (both halves compute S for u) ----
    const int base = atom * NA;
    float x = dR[(base + u) * 3 + 0];
    float y = dR[(base + u) * 3 + 1];
    float z = dR[(base + u) * 3 + 2];
    int   nb = neigh[base + u];
    float Rij = x * x + y * y + z * z;          // squared distance (ref quirk)
    bool  mask = nb > 0;
    bool  mask_min = Rij < RMINF;
    float safe = (Rij > 0.f) ? Rij : 1.f;
    float s_inv = 1.f / safe;
    float s_cos = 0.5f * cosf((Rij - RMINF) * PI_OVER_DR) + 0.5f;
    float S = (mask && mask_min) ? s_inv
            : ((!mask_min && Rij < RMAXF) ? s_cos : 0.f);

    unsigned long long bal = __ballot(mask);
    if (t < 128 && (t & 63) == 0) balls[t >> 6] = bal;
    __syncthreads();   // #1: balls visible

    unsigned long long nb0 = ~balls[0], nb1 = ~balls[1];
    int firstBad;
    if (nb0)       firstBad = __ffsll((long long)nb0) - 1;
    else if (nb1)  firstBad = 64 + __ffsll((long long)nb1) - 1;
    else           firstBad = 128;

    if (half == 0) {
        float f = (u < firstBad) ? (S * s_inv) : 0.f;
        RiSh[u] = make_float4(S, f * x, f * y, f * z);
    } else {
        // table coordinate: u' = S/(1+S) in [0,1); pos in [0, NK)
        float uu = S * __builtin_amdgcn_rcpf(1.f + S);
        uu = S / (1.f + S);                      // exact divide (match prep map)
        float pos = fminf(uu * (float)NK, (float)NK - 0.001f);
        float fi = floorf(pos);
        IFSh[u] = make_float2(pos - fi, fi);
    }
    __syncthreads();   // #2: RiSh + IFSh ready

    // ---- phase B: tmpB[c][j], j = u (active j<100), a split by half ----
    float a0 = 0.f, a1 = 0.f, a2 = 0.f, a3 = 0.f;
    if (u < 100) {
        const int ab = half * 64;
        #pragma unroll 4
        for (int aa = 0; aa < 64; ++aa) {
            int a = ab + aa;
            float2 ifv = IFSh[a];
            float4 ri = RiSh[a];
            int ia = (int)ifv.y;
            const float* trow = TBL + ia * 100 + u;
            float t0 = trow[0];
            float t1 = trow[100];
            float g = fmaf(ifv.x, t1 - t0, t0);
            a0 = fmaf(ri.x, g, a0);
            a1 = fmaf(ri.y, g, a1);
            a2 = fmaf(ri.z, g, a2);
            a3 = fmaf(ri.w, g, a3);
        }
        tmpBSh[half][0][u] = a0;
        tmpBSh[half][1][u] = a1;
        tmpBSh[half][2][u] = a2;
        tmpBSh[half][3][u] = a3;
    }
    __syncthreads();   // #3

    if (half == 0 && u < 100) {
        #pragma unroll
        for (int c = 0; c < 4; ++c)
            tmpBSh[0][c][u] += tmpBSh[1][c][u];
    }
    __syncthreads();   // #4

    // ---- phase C: DR[i][M] -> bf16 hi/lo planes; i split by half ----
    if (u < 100) {
        float b0 = tmpBSh[0][0][u];
        float b1 = tmpBSh[0][1][u];
        float b2 = tmpBSh[0][2][u];
        float b3 = tmpBSh[0][3][u];
        uint16_t* dh = DRhi + (size_t)atom * 1600;
        uint16_t* dl = DRlo + (size_t)atom * 1600;
        const int i0 = half * 8;
        #pragma unroll
        for (int ii = 0; ii < 8; ++ii) {
            int i = i0 + ii;
            float v = tmpBSh[0][0][i] * b0 + tmpBSh[0][1][i] * b1
                    + tmpBSh[0][2][i] * b2 + tmpBSh[0][3][i] * b3;
            uint16_t hi = bf16_of(v);
            dh[i * 100 + u] = hi;
            dl[i * 100 + u] = bf16_of(v - bf16_to_f(hi));
        }
    }
}

// ---------------------------------------------------------------------------
// Fitting GEMM via split-bf16 MFMA, LDS-free (frags direct from global/L2).
// O[8192][256] = tanh(A[8192][KP] @ Wt^T + bias) as bf16 hi/lo planes.
// Grid (128, 2); 512 threads = 8 waves = 2 m-groups x 4 n-groups; BM=64 BN=128.
// ---------------------------------------------------------------------------
template<int KP>
__global__ __launch_bounds__(512, 4) void gemm_mfma_tanh(
    const uint16_t* __restrict__ Ahi, const uint16_t* __restrict__ Alo,
    const uint16_t* __restrict__ Wthi, const uint16_t* __restrict__ Wtlo,
    const float* __restrict__ bias,
    uint16_t* __restrict__ Ohi, uint16_t* __restrict__ Olo)
{
    const int tid = threadIdx.x;
    const int wid = tid >> 6, lane = tid & 63;
    const int mg = wid >> 2, ng = wid & 3;
    const int ar = lane & 15, kg = lane >> 4;
    const int row0 = blockIdx.x * 64 + mg * 32;
    const int col0 = blockIdx.y * 128 + ng * 32;

    f32x4 acc[2][2];
    #pragma unroll
    for (int m = 0; m < 2; ++m)
        #pragma unroll
        for (int n = 0; n < 2; ++n) acc[m][n] = (f32x4){0.f, 0.f, 0.f, 0.f};

    size_t abase[2], bbase[2];
    #pragma unroll
    for (int m = 0; m < 2; ++m) abase[m] = (size_t)(row0 + m * 16 + ar) * KP + kg * 8;
    #pragma unroll
    for (int n = 0; n < 2; ++n) bbase[n] = (size_t)(col0 + n * 16 + ar) * KP + kg * 8;

    #pragma unroll 2
    for (int k0 = 0; k0 < KP; k0 += 32) {
        short8v ah[2], al[2], bh[2], bl[2];
        #pragma unroll
        for (int m = 0; m < 2; ++m) {
            ah[m] = *(const short8v*)(Ahi + abase[m] + k0);
            al[m] = *(const short8v*)(Alo + abase[m] + k0);
        }
        #pragma unroll
        for (int n = 0; n < 2; ++n) {
            bh[n] = *(const short8v*)(Wthi + bbase[n] + k0);
            bl[n] = *(const short8v*)(Wtlo + bbase[n] + k0);
        }
        #pragma unroll
        for (int m = 0; m < 2; ++m)
            #pragma unroll
            for (int n = 0; n < 2; ++n) {
                acc[m][n] = __builtin_amdgcn_mfma_f32_16x16x32_bf16(ah[m], bh[n], acc[m][n], 0, 0, 0);
                acc[m][n] = __builtin_amdgcn_mfma_f32_16x16x32_bf16(ah[m], bl[n], acc[m][n], 0, 0, 0);
                acc[m][n] = __builtin_amdgcn_mfma_f32_16x16x32_bf16(al[m], bh[n], acc[m][n], 0, 0, 0);
            }
    }

    // epilogue: D row = m*16 + kg*4 + r, col = n*16 + ar
    #pragma unroll
    for (int n = 0; n < 2; ++n) {
        int col = col0 + n * 16 + ar;
        bool valid = col < 240;
        float bv = valid ? bias[col] : 0.f;
        #pragma unroll
        for (int m = 0; m < 2; ++m) {
            #pragma unroll
            for (int r = 0; r < 4; ++r) {
                int row = row0 + m * 16 + kg * 4 + r;
                float v = valid ? fast_tanh(acc[m][n][r] + bv) : 0.f;
                uint16_t hi = bf16_of(v);
                Ohi[(size_t)row * 256 + col] = hi;
                Olo[(size_t)row * 256 + col] = bf16_of(v - bf16_to_f(hi));
            }
        }
    }
}

// ---------------------------------------------------------------------------
// Ei = (h_hi+h_lo) @ Wf3 + bf3 : one wave per atom, shuffle reduce.
// ---------------------------------------------------------------------------
__global__ __launch_bounds__(256) void final_dot_kernel(
    const uint16_t* __restrict__ Hhi, const uint16_t* __restrict__ Hlo,
    const float* __restrict__ Wf3, const float* __restrict__ bf3,
    float* __restrict__ out)
{
    int wave = threadIdx.x >> 6, lane = threadIdx.x & 63;
    int atom = blockIdx.x * 4 + wave;
    float v = 0.f;
    if (lane < 60) {
        const uint16_t* ph = Hhi + (size_t)atom * 256 + lane * 4;
        const uint16_t* pl = Hlo + (size_t)atom * 256 + lane * 4;
        ushort4 h4 = *(const ushort4*)ph;
        ushort4 l4 = *(const ushort4*)pl;
        float4 w = *(const float4*)&Wf3[lane * 4];
        v = (bf16_to_f(h4.x) + bf16_to_f(l4.x)) * w.x
          + (bf16_to_f(h4.y) + bf16_to_f(l4.y)) * w.y
          + (bf16_to_f(h4.z) + bf16_to_f(l4.z)) * w.z
          + (bf16_to_f(h4.w) + bf16_to_f(l4.w)) * w.w;
    }
    #pragma unroll
    for (int off = 32; off; off >>= 1) v += __shfl_down(v, off, 64);
    if (lane == 0) out[4 + atom] = v + bf3[0];
}

__global__ __launch_bounds__(256) void etot_kernel(float* __restrict__ out)
{
    __shared__ float red[256];
    int b = blockIdx.x, t = threadIdx.x;
    float s = 0.f;
    for (int i = t; i < NN; i += 256) s += out[4 + b * NN + i];
    red[t] = s;
    __syncthreads();
    for (int w = 128; w; w >>= 1) {
        if (t < w) red[t] += red[t + w];
        __syncthreads();
    }
    if (t == 0) out[b] = red[0];
}

// ---------------------------------------------------------------------------
extern "C" void kernel_launch(void* const* d_in, const int* in_sizes, int n_in,
                              void* d_out, int out_size, void* d_ws, size_t ws_size,
                              hipStream_t stream)
{
    const float* dR    = (const float*)d_in[0];
    const int*   neigh = (const int*)d_in[1];
    const float* We0   = (const float*)d_in[2];
    const float* be0   = (const float*)d_in[3];
    const float* We1   = (const float*)d_in[4];
    const float* be1   = (const float*)d_in[5];
    const float* We2   = (const float*)d_in[6];
    const float* be2   = (const float*)d_in[7];
    const float* Wf0   = (const float*)d_in[8];
    const float* bf0   = (const float*)d_in[9];
    const float* Wf1   = (const float*)d_in[10];
    const float* bf1   = (const float*)d_in[11];
    const float* Wf2   = (const float*)d_in[12];
    const float* bf2   = (const float*)d_in[13];
    const float* Wf3   = (const float*)d_in[14];
    const float* bf3   = (const float*)d_in[15];
    float* out = (float*)d_out;

    char* ws = (char*)d_ws;
    uint16_t* Wt0hi  = (uint16_t*)(ws + 32768);               // 819200
    uint16_t* Wt0lo  = (uint16_t*)(ws + 851968);              // 819200
    uint16_t* Wt1hi  = (uint16_t*)(ws + 1671168);             // 131072
    uint16_t* Wt1lo  = (uint16_t*)(ws + 1802240);             // 131072
    uint16_t* Wt2hi  = (uint16_t*)(ws + 1933312);             // 131072
    uint16_t* Wt2lo  = (uint16_t*)(ws + 2064384);             // 131072
    uint16_t* DRhi   = (uint16_t*)(ws + 2195456);             // 26214400
    uint16_t* DRlo   = (uint16_t*)(ws + 28409856);            // 26214400
    uint16_t* hAhi   = (uint16_t*)(ws + 54624256);            // 4194304
    uint16_t* hAlo   = (uint16_t*)(ws + 58818560);            // 4194304
    uint16_t* hBhi   = (uint16_t*)(ws + 63012864);            // 4194304
    uint16_t* hBlo   = (uint16_t*)(ws + 67207168);            // 4194304
    // TBL (2049*100*4 = 819600 B) aliases the hBhi slot: written by
    // prep_table, read only by desc_kernel, then overwritten by gemm2.
    float* TBL = (float*)(ws + 63012864);

    prep_table_kernel<<<33, 256, 0, stream>>>(We0, be0, We1, be1, We2, be2, TBL);
    prep_wt_kernel<<<1600, 256, 0, stream>>>(Wf0, Wt0hi, Wt0lo, 1600, 1600);
    prep_wt_kernel<<<256, 256, 0, stream>>>(Wf1, Wt1hi, Wt1lo, 240, 256);
    prep_wt_kernel<<<256, 256, 0, stream>>>(Wf2, Wt2hi, Wt2lo, 240, 256);

    desc_kernel<<<NB * NN, 256, 0, stream>>>(dR, neigh, TBL, DRhi, DRlo);

    gemm_mfma_tanh<1600><<<dim3(128, 2), 512, 0, stream>>>(DRhi, DRlo, Wt0hi, Wt0lo, bf0, hAhi, hAlo);
    gemm_mfma_tanh<256><<<dim3(128, 2), 512, 0, stream>>>(hAhi, hAlo, Wt1hi, Wt1lo, bf1, hBhi, hBlo);
    gemm_mfma_tanh<256><<<dim3(128, 2), 512, 0, stream>>>(hBhi, hBlo, Wt2hi, Wt2lo, bf2, hAhi, hAlo);

    final_dot_kernel<<<NB * NN / 4, 256, 0, stream>>>(hAhi, hAlo, Wf3, bf3, out);
    etot_kernel<<<NB, 256, 0, stream>>>(out);
}